// Round 6
// baseline (2687.272 us; speedup 1.0000x reference)
//
#include <hip/hip_runtime.h>
#include <math.h>

#define N_NODES 131072
#define N_EDGES 2097152
#define S_SEG   512
#define F_INPUT 64
#define HID     128
#define EMB     128
#define RNN_HID 256

// ---------------------------------------------------------------------------
// Graph preprocessing: counts + weighted degree
// ---------------------------------------------------------------------------
__global__ void zero_kernel(int* __restrict__ cnt, float* __restrict__ degw, int n) {
    int i = blockIdx.x * blockDim.x + threadIdx.x;
    if (i < n) { cnt[i] = 0; degw[i] = 0.f; }
}

__global__ void count_kernel(const int* __restrict__ dst, const float* __restrict__ ew,
                             int* __restrict__ cnt, float* __restrict__ degw, int e) {
    int i = blockIdx.x * blockDim.x + threadIdx.x;
    if (i < e) {
        int d = dst[i];
        atomicAdd(&cnt[d], 1);
        atomicAdd(&degw[d], ew[i]);
    }
}

// exclusive scan of cnt[n] -> row_ptr[n+1]; cnt becomes cursor (copy of row_ptr)
__global__ __launch_bounds__(1024) void scan_kernel(int* __restrict__ cnt,
                                                    int* __restrict__ row_ptr, int n) {
    __shared__ int sums[1024];
    int tid = threadIdx.x;
    int per = n / 1024;            // 128
    int base = tid * per;
    int s = 0;
    for (int k = 0; k < per; k++) s += cnt[base + k];
    sums[tid] = s;
    __syncthreads();
    for (int off = 1; off < 1024; off <<= 1) {
        int v = (tid >= off) ? sums[tid - off] : 0;
        __syncthreads();
        sums[tid] += v;
        __syncthreads();
    }
    int run = (tid > 0) ? sums[tid - 1] : 0;
    for (int k = 0; k < per; k++) {
        int v = cnt[base + k];
        row_ptr[base + k] = run;
        cnt[base + k] = run;       // cursor
        run += v;
    }
    if (tid == 1023) row_ptr[n] = run;
}

__global__ void dinv_kernel(const float* __restrict__ degw, float* __restrict__ dinv, int n) {
    int i = blockIdx.x * blockDim.x + threadIdx.x;
    if (i < n) dinv[i] = rsqrtf(degw[i] + 1.0f);   // +1 = self-loop weight
}

__global__ void scatter_kernel(const int* __restrict__ src, const int* __restrict__ dst,
                               const float* __restrict__ ew, int* __restrict__ cursor,
                               int* __restrict__ col, float* __restrict__ wv, int e) {
    int i = blockIdx.x * blockDim.x + threadIdx.x;
    if (i < e) {
        int d = dst[i];
        int p = atomicAdd(&cursor[d], 1);
        col[p] = src[i];
        wv[p]  = ew[i];
    }
}

// ---------------------------------------------------------------------------
// Dense GEMM: Y[M x 128] = X[M x K] @ W[K x 128], K in {64,128}, M % 64 == 0
// ---------------------------------------------------------------------------
__global__ __launch_bounds__(256) void gemm_kernel(const float* __restrict__ X,
                                                   const float* __restrict__ W,
                                                   float* __restrict__ Y, int K) {
    __shared__ float Xs[64][68];   // [k][m], padded
    __shared__ float Ws[64][128];  // [k][n]
    int tid = threadIdx.x;
    int m0 = blockIdx.x * 64;
    int tr = tid >> 5;             // 0..7
    int tc = tid & 31;             // 0..31
    int r0 = tr * 8;
    int c0 = tc * 4;
    float acc[8][4];
#pragma unroll
    for (int i = 0; i < 8; i++)
#pragma unroll
        for (int j = 0; j < 4; j++) acc[i][j] = 0.f;

    for (int kt = 0; kt < K; kt += 64) {
#pragma unroll
        for (int i = 0; i < 4; i++) {
            int lin = i * 256 + tid;
            int row = lin >> 4;
            int kq  = lin & 15;
            float4 v = *(const float4*)&X[(size_t)(m0 + row) * K + kt + kq * 4];
            Xs[kq * 4 + 0][row] = v.x;
            Xs[kq * 4 + 1][row] = v.y;
            Xs[kq * 4 + 2][row] = v.z;
            Xs[kq * 4 + 3][row] = v.w;
        }
#pragma unroll
        for (int i = 0; i < 8; i++) {
            int lin = i * 256 + tid;
            int kk = lin >> 5;
            int cq = lin & 31;
            *(float4*)&Ws[kk][cq * 4] = *(const float4*)&W[(size_t)(kt + kk) * 128 + cq * 4];
        }
        __syncthreads();
#pragma unroll
        for (int k = 0; k < 64; k++) {
            float4 b  = *(const float4*)&Ws[k][c0];
            float4 a0 = *(const float4*)&Xs[k][r0];
            float4 a1 = *(const float4*)&Xs[k][r0 + 4];
            float a[8] = {a0.x, a0.y, a0.z, a0.w, a1.x, a1.y, a1.z, a1.w};
            float bb[4] = {b.x, b.y, b.z, b.w};
#pragma unroll
            for (int i = 0; i < 8; i++)
#pragma unroll
                for (int j = 0; j < 4; j++) acc[i][j] += a[i] * bb[j];
        }
        __syncthreads();
    }
#pragma unroll
    for (int i = 0; i < 8; i++) {
        float4 v = make_float4(acc[i][0], acc[i][1], acc[i][2], acc[i][3]);
        *(float4*)&Y[(size_t)(m0 + r0 + i) * 128 + c0] = v;
    }
}

// ---------------------------------------------------------------------------
// SpMM: out[i][:] = relu( dinv[i]^2*t[i][:] + sum_e dinv[i]*w_e*dinv[col_e]*t[col_e][:] + b )
// ---------------------------------------------------------------------------
__global__ __launch_bounds__(256) void spmm_kernel(const float* __restrict__ t,
                                                   const int* __restrict__ row_ptr,
                                                   const int* __restrict__ col,
                                                   const float* __restrict__ wv,
                                                   const float* __restrict__ dinv,
                                                   const float* __restrict__ bias,
                                                   float* __restrict__ out) {
    int wave = threadIdx.x >> 6;
    int lane = threadIdx.x & 63;
    int i = blockIdx.x * 4 + wave;
    int f = lane * 2;
    float di = dinv[i];
    float2 self = *(const float2*)&t[(size_t)i * HID + f];
    float sc = di * di;
    float ax = sc * self.x, ay = sc * self.y;
    int p0 = row_ptr[i], p1 = row_ptr[i + 1];
    for (int p = p0; p < p1; p++) {
        int c = col[p];
        float coef = di * wv[p] * dinv[c];
        float2 v = *(const float2*)&t[(size_t)c * HID + f];
        ax += coef * v.x;
        ay += coef * v.y;
    }
    float2 b = *(const float2*)&bias[f];
    ax = fmaxf(ax + b.x, 0.f);
    ay = fmaxf(ay + b.y, 0.f);
    float2 r; r.x = ax; r.y = ay;
    *(float2*)&out[(size_t)i * HID + f] = r;
}

// ---------------------------------------------------------------------------
// Segment starts via binary search on sorted batch
// ---------------------------------------------------------------------------
__global__ void segstart_kernel(const int* __restrict__ batch, int* __restrict__ seg, int n) {
    int s = blockIdx.x * blockDim.x + threadIdx.x;
    if (s <= S_SEG) {
        int lo = 0, hi = n;
        while (lo < hi) {
            int m = (lo + hi) >> 1;
            if (batch[m] < s) lo = m + 1; else hi = m;
        }
        seg[s] = lo;
    }
}

__global__ __launch_bounds__(128) void pool_kernel(const float* __restrict__ z,
                                                   const int* __restrict__ seg,
                                                   float* __restrict__ pooled) {
    int s = blockIdx.x;
    int fidx = threadIdx.x;
    int a = seg[s], b = seg[s + 1];
    float sum = 0.f;
    for (int r = a; r < b; r++) sum += z[(size_t)r * HID + fidx];
    float cnt = (float)(b - a);
    pooled[(size_t)s * EMB + fidx] = sum / fmaxf(cnt, 1.f);
}

// ---------------------------------------------------------------------------
// Precompute U[t][j] = pooled[t] . Wih[j] + bih[j] + bhh[j]   (hoists the
// input-projection out of the serial RNN loop; fully parallel GEMM-shape)
// ---------------------------------------------------------------------------
__global__ __launch_bounds__(256) void ucomp_kernel(const float* __restrict__ pooled,
                                                    const float* __restrict__ Wih,
                                                    const float* __restrict__ bih,
                                                    const float* __restrict__ bhh,
                                                    float* __restrict__ U) {
    __shared__ float xs[EMB];
    int t = blockIdx.x;
    int j = threadIdx.x;
    if (j < EMB) xs[j] = pooled[(size_t)t * EMB + j];
    __syncthreads();
    const float* wr = Wih + (size_t)j * EMB;
    float a0 = 0.f, a1 = 0.f, a2 = 0.f, a3 = 0.f;
#pragma unroll
    for (int k = 0; k < EMB; k += 16) {
        float4 w0 = *(const float4*)&wr[k];
        float4 w1 = *(const float4*)&wr[k + 4];
        float4 w2 = *(const float4*)&wr[k + 8];
        float4 w3 = *(const float4*)&wr[k + 12];
        a0 += w0.x * xs[k]      + w0.y * xs[k + 1]  + w0.z * xs[k + 2]  + w0.w * xs[k + 3];
        a1 += w1.x * xs[k + 4]  + w1.y * xs[k + 5]  + w1.z * xs[k + 6]  + w1.w * xs[k + 7];
        a2 += w2.x * xs[k + 8]  + w2.y * xs[k + 9]  + w2.z * xs[k + 10] + w2.w * xs[k + 11];
        a3 += w3.x * xs[k + 12] + w3.y * xs[k + 13] + w3.z * xs[k + 14] + w3.w * xs[k + 15];
    }
    U[(size_t)t * RNN_HID + j] = ((a0 + a1) + (a2 + a3)) + bih[j] + bhh[j];
}

// ---------------------------------------------------------------------------
// Serial tanh RNN: h_{t} = tanh(U[t] + Whh @ h_{t-1})
// 1024 threads (16 waves, 4/SIMD). Thread (j = tid>>2, q = tid&3) holds 64
// Whh weights in VGPRs, in a chunk-rotated order so each wave's ds_read_b128
// hits 16 distinct 16B chunks across all 32 banks (<=2-way, free).
// Double-buffered h -> one barrier per step. U[t+1] prefetched during step t.
// ---------------------------------------------------------------------------
__global__ __launch_bounds__(1024, 4) void rnn_kernel(const float* __restrict__ U,
                                                      const float* __restrict__ Whh,
                                                      float* __restrict__ hs) {
    __shared__ float hb[2][RNN_HID];
    int tid = threadIdx.x;
    int j = tid >> 2;          // output index 0..255
    int q = tid & 3;           // quarter of the k-dimension
    int cbase = q * 16 + ((j & 3) << 2);   // rotated chunk base (chunk = 4 floats)

    float4 w[16];
#pragma unroll
    for (int ii = 0; ii < 16; ii++) {
        int ck = (cbase + ii) & 63;
        w[ii] = *(const float4*)&Whh[(size_t)j * RNN_HID + ck * 4];
    }

    if (tid < RNN_HID) hb[0][tid] = 0.f;
    __syncthreads();

    float u_next = U[j];       // t = 0
    int p = 0;
    for (int t = 0; t < S_SEG; t++) {
        float u = u_next;
        if (t + 1 < S_SEG) u_next = U[(size_t)(t + 1) * RNN_HID + j];
        float a0 = 0.f, a1 = 0.f, a2 = 0.f, a3 = 0.f;
#pragma unroll
        for (int ii = 0; ii < 16; ii += 4) {
            int c0 = (cbase + ii)     & 63;
            int c1 = (cbase + ii + 1) & 63;
            int c2 = (cbase + ii + 2) & 63;
            int c3 = (cbase + ii + 3) & 63;
            float4 h0 = *(const float4*)&hb[p][c0 * 4];
            float4 h1 = *(const float4*)&hb[p][c1 * 4];
            float4 h2 = *(const float4*)&hb[p][c2 * 4];
            float4 h3 = *(const float4*)&hb[p][c3 * 4];
            float4 w0 = w[ii], w1 = w[ii + 1], w2 = w[ii + 2], w3 = w[ii + 3];
            a0 += w0.x * h0.x + w0.y * h0.y + w0.z * h0.z + w0.w * h0.w;
            a1 += w1.x * h1.x + w1.y * h1.y + w1.z * h1.z + w1.w * h1.w;
            a2 += w2.x * h2.x + w2.y * h2.y + w2.z * h2.z + w2.w * h2.w;
            a3 += w3.x * h3.x + w3.y * h3.y + w3.z * h3.z + w3.w * h3.w;
        }
        float acc = (a0 + a1) + (a2 + a3);
        acc += __shfl_xor(acc, 1, 64);
        acc += __shfl_xor(acc, 2, 64);
        if (q == 0) {
            float hn = tanhf(acc + u);
            hb[p ^ 1][j] = hn;
            hs[(size_t)t * RNN_HID + j] = hn;
        }
        __syncthreads();
        p ^= 1;
    }
}

// ---------------------------------------------------------------------------
// Final linear + sigmoid: one wave per sequence position
// ---------------------------------------------------------------------------
__global__ __launch_bounds__(256) void logits_kernel(const float* __restrict__ hs,
                                                     const float* __restrict__ Wl,
                                                     const float* __restrict__ bl,
                                                     float* __restrict__ out) {
    int tid = threadIdx.x;
    int wave = tid >> 6, lane = tid & 63;
    int s = blockIdx.x * 4 + wave;
    float4 h = ((const float4*)&hs[(size_t)s * RNN_HID])[lane];
    float4 w0 = ((const float4*)Wl)[lane];
    float4 w1 = ((const float4*)(Wl + RNN_HID))[lane];
    float a0 = h.x * w0.x + h.y * w0.y + h.z * w0.z + h.w * w0.w;
    float a1 = h.x * w1.x + h.y * w1.y + h.z * w1.z + h.w * w1.w;
#pragma unroll
    for (int off = 32; off; off >>= 1) {
        a0 += __shfl_xor(a0, off, 64);
        a1 += __shfl_xor(a1, off, 64);
    }
    if (lane == 0) {
        out[s * 2 + 0] = 1.f / (1.f + expf(-(a0 + bl[0])));
        out[s * 2 + 1] = 1.f / (1.f + expf(-(a1 + bl[1])));
    }
}

// ---------------------------------------------------------------------------
extern "C" void kernel_launch(void* const* d_in, const int* in_sizes, int n_in,
                              void* d_out, int out_size, void* d_ws, size_t ws_size,
                              hipStream_t stream) {
    const float* x    = (const float*)d_in[0];
    const float* ew   = (const float*)d_in[1];
    const int*   src  = (const int*)d_in[2];
    const int*   dst  = (const int*)d_in[3];
    const int*   batch= (const int*)d_in[4];
    const float* W1   = (const float*)d_in[5];
    const float* b1   = (const float*)d_in[6];
    const float* W2   = (const float*)d_in[7];
    const float* b2   = (const float*)d_in[8];
    const float* W3   = (const float*)d_in[9];
    const float* b3   = (const float*)d_in[10];
    const float* Wih  = (const float*)d_in[11];
    const float* Whh  = (const float*)d_in[12];
    const float* bih  = (const float*)d_in[13];
    const float* bhh  = (const float*)d_in[14];
    const float* Wl   = (const float*)d_in[15];
    const float* bl   = (const float*)d_in[16];
    float* out = (float*)d_out;
    (void)in_sizes; (void)n_in; (void)out_size; (void)ws_size;

    char* ws = (char*)d_ws;
    size_t o = 0;
    auto alloc = [&](size_t bytes) -> char* {
        o = (o + 255) & ~(size_t)255;
        char* p = ws + o;
        o += bytes;
        return p;
    };
    float* bufA   = (float*)alloc((size_t)N_NODES * HID * 4);
    float* bufB   = (float*)alloc((size_t)N_NODES * HID * 4);
    int*   colA   = (int*)  alloc((size_t)N_EDGES * 4);
    float* wvA    = (float*)alloc((size_t)N_EDGES * 4);
    int*   rowp   = (int*)  alloc((size_t)(N_NODES + 1) * 4);
    int*   cursor = (int*)  alloc((size_t)N_NODES * 4);
    float* degw   = (float*)alloc((size_t)N_NODES * 4);
    float* dinv   = (float*)alloc((size_t)N_NODES * 4);
    int*   seg    = (int*)  alloc((size_t)(S_SEG + 1) * 4);
    float* pooled = (float*)alloc((size_t)S_SEG * EMB * 4);
    float* hs     = (float*)alloc((size_t)S_SEG * RNN_HID * 4);
    float* U      = (float*)alloc((size_t)S_SEG * RNN_HID * 4);

    // --- CSR build ---
    zero_kernel<<<(N_NODES + 255) / 256, 256, 0, stream>>>(cursor, degw, N_NODES);
    count_kernel<<<(N_EDGES + 255) / 256, 256, 0, stream>>>(dst, ew, cursor, degw, N_EDGES);
    scan_kernel<<<1, 1024, 0, stream>>>(cursor, rowp, N_NODES);
    dinv_kernel<<<(N_NODES + 255) / 256, 256, 0, stream>>>(degw, dinv, N_NODES);
    scatter_kernel<<<(N_EDGES + 255) / 256, 256, 0, stream>>>(src, dst, ew, cursor, colA, wvA, N_EDGES);

    // --- GCN layers ---
    gemm_kernel<<<N_NODES / 64, 256, 0, stream>>>(x, W1, bufA, F_INPUT);
    spmm_kernel<<<N_NODES / 4, 256, 0, stream>>>(bufA, rowp, colA, wvA, dinv, b1, bufB);
    gemm_kernel<<<N_NODES / 64, 256, 0, stream>>>(bufB, W2, bufA, HID);
    spmm_kernel<<<N_NODES / 4, 256, 0, stream>>>(bufA, rowp, colA, wvA, dinv, b2, bufB);
    gemm_kernel<<<N_NODES / 64, 256, 0, stream>>>(bufB, W3, bufA, HID);
    spmm_kernel<<<N_NODES / 4, 256, 0, stream>>>(bufA, rowp, colA, wvA, dinv, b3, bufB);

    // --- mean pool per subgraph ---
    segstart_kernel<<<(S_SEG + 1 + 255) / 256, 256, 0, stream>>>(batch, seg, N_NODES);
    pool_kernel<<<S_SEG, 128, 0, stream>>>(bufB, seg, pooled);

    // --- RNN: hoisted input projection, then serial loop ---
    ucomp_kernel<<<S_SEG, 256, 0, stream>>>(pooled, Wih, bih, bhh, U);
    rnn_kernel<<<1, 1024, 0, stream>>>(U, Whh, hs);
    logits_kernel<<<S_SEG / 4, 256, 0, stream>>>(hs, Wl, bl, out);
}

// Round 9
// 2517.292 us; speedup vs baseline: 1.0675x; 1.0675x over previous
//
#include <hip/hip_runtime.h>
#include <math.h>

#define N_NODES 131072
#define N_EDGES 2097152
#define S_SEG   512
#define F_INPUT 64
#define HID     128
#define EMB     128
#define RNN_HID 256

// ---------------------------------------------------------------------------
// Graph preprocessing: counts + weighted degree
// ---------------------------------------------------------------------------
__global__ void zero_kernel(int* __restrict__ cnt, float* __restrict__ degw, int n) {
    int i = blockIdx.x * blockDim.x + threadIdx.x;
    if (i < n) { cnt[i] = 0; degw[i] = 0.f; }
}

__global__ void count_kernel(const int* __restrict__ dst, const float* __restrict__ ew,
                             int* __restrict__ cnt, float* __restrict__ degw, int e) {
    int i = blockIdx.x * blockDim.x + threadIdx.x;
    if (i < e) {
        int d = dst[i];
        atomicAdd(&cnt[d], 1);
        atomicAdd(&degw[d], ew[i]);
    }
}

// exclusive scan of cnt[n] -> row_ptr[n+1]; cnt becomes cursor (copy of row_ptr)
__global__ __launch_bounds__(1024) void scan_kernel(int* __restrict__ cnt,
                                                    int* __restrict__ row_ptr, int n) {
    __shared__ int sums[1024];
    int tid = threadIdx.x;
    int per = n / 1024;            // 128
    int base = tid * per;
    int s = 0;
    for (int k = 0; k < per; k++) s += cnt[base + k];
    sums[tid] = s;
    __syncthreads();
    for (int off = 1; off < 1024; off <<= 1) {
        int v = (tid >= off) ? sums[tid - off] : 0;
        __syncthreads();
        sums[tid] += v;
        __syncthreads();
    }
    int run = (tid > 0) ? sums[tid - 1] : 0;
    for (int k = 0; k < per; k++) {
        int v = cnt[base + k];
        row_ptr[base + k] = run;
        cnt[base + k] = run;       // cursor
        run += v;
    }
    if (tid == 1023) row_ptr[n] = run;
}

__global__ void dinv_kernel(const float* __restrict__ degw, float* __restrict__ dinv, int n) {
    int i = blockIdx.x * blockDim.x + threadIdx.x;
    if (i < n) dinv[i] = rsqrtf(degw[i] + 1.0f);   // +1 = self-loop weight
}

__global__ void scatter_kernel(const int* __restrict__ src, const int* __restrict__ dst,
                               const float* __restrict__ ew, int* __restrict__ cursor,
                               int* __restrict__ col, float* __restrict__ wv, int e) {
    int i = blockIdx.x * blockDim.x + threadIdx.x;
    if (i < e) {
        int d = dst[i];
        int p = atomicAdd(&cursor[d], 1);
        col[p] = src[i];
        wv[p]  = ew[i];
    }
}

// ---------------------------------------------------------------------------
// Dense GEMM: Y[M x 128] = X[M x K] @ W[K x 128], K in {64,128}, M % 64 == 0
// ---------------------------------------------------------------------------
__global__ __launch_bounds__(256) void gemm_kernel(const float* __restrict__ X,
                                                   const float* __restrict__ W,
                                                   float* __restrict__ Y, int K) {
    __shared__ float Xs[64][68];   // [k][m], padded
    __shared__ float Ws[64][128];  // [k][n]
    int tid = threadIdx.x;
    int m0 = blockIdx.x * 64;
    int tr = tid >> 5;             // 0..7
    int tc = tid & 31;             // 0..31
    int r0 = tr * 8;
    int c0 = tc * 4;
    float acc[8][4];
#pragma unroll
    for (int i = 0; i < 8; i++)
#pragma unroll
        for (int j = 0; j < 4; j++) acc[i][j] = 0.f;

    for (int kt = 0; kt < K; kt += 64) {
#pragma unroll
        for (int i = 0; i < 4; i++) {
            int lin = i * 256 + tid;
            int row = lin >> 4;
            int kq  = lin & 15;
            float4 v = *(const float4*)&X[(size_t)(m0 + row) * K + kt + kq * 4];
            Xs[kq * 4 + 0][row] = v.x;
            Xs[kq * 4 + 1][row] = v.y;
            Xs[kq * 4 + 2][row] = v.z;
            Xs[kq * 4 + 3][row] = v.w;
        }
#pragma unroll
        for (int i = 0; i < 8; i++) {
            int lin = i * 256 + tid;
            int kk = lin >> 5;
            int cq = lin & 31;
            *(float4*)&Ws[kk][cq * 4] = *(const float4*)&W[(size_t)(kt + kk) * 128 + cq * 4];
        }
        __syncthreads();
#pragma unroll
        for (int k = 0; k < 64; k++) {
            float4 b  = *(const float4*)&Ws[k][c0];
            float4 a0 = *(const float4*)&Xs[k][r0];
            float4 a1 = *(const float4*)&Xs[k][r0 + 4];
            float a[8] = {a0.x, a0.y, a0.z, a0.w, a1.x, a1.y, a1.z, a1.w};
            float bb[4] = {b.x, b.y, b.z, b.w};
#pragma unroll
            for (int i = 0; i < 8; i++)
#pragma unroll
                for (int j = 0; j < 4; j++) acc[i][j] += a[i] * bb[j];
        }
        __syncthreads();
    }
#pragma unroll
    for (int i = 0; i < 8; i++) {
        float4 v = make_float4(acc[i][0], acc[i][1], acc[i][2], acc[i][3]);
        *(float4*)&Y[(size_t)(m0 + r0 + i) * 128 + c0] = v;
    }
}

// ---------------------------------------------------------------------------
// SpMM: out[i][:] = relu( dinv[i]^2*t[i][:] + sum_e dinv[i]*w_e*dinv[col_e]*t[col_e][:] + b )
// ---------------------------------------------------------------------------
__global__ __launch_bounds__(256) void spmm_kernel(const float* __restrict__ t,
                                                   const int* __restrict__ row_ptr,
                                                   const int* __restrict__ col,
                                                   const float* __restrict__ wv,
                                                   const float* __restrict__ dinv,
                                                   const float* __restrict__ bias,
                                                   float* __restrict__ out) {
    int wave = threadIdx.x >> 6;
    int lane = threadIdx.x & 63;
    int i = blockIdx.x * 4 + wave;
    int f = lane * 2;
    float di = dinv[i];
    float2 self = *(const float2*)&t[(size_t)i * HID + f];
    float sc = di * di;
    float ax = sc * self.x, ay = sc * self.y;
    int p0 = row_ptr[i], p1 = row_ptr[i + 1];
    for (int p = p0; p < p1; p++) {
        int c = col[p];
        float coef = di * wv[p] * dinv[c];
        float2 v = *(const float2*)&t[(size_t)c * HID + f];
        ax += coef * v.x;
        ay += coef * v.y;
    }
    float2 b = *(const float2*)&bias[f];
    ax = fmaxf(ax + b.x, 0.f);
    ay = fmaxf(ay + b.y, 0.f);
    float2 r; r.x = ax; r.y = ay;
    *(float2*)&out[(size_t)i * HID + f] = r;
}

// ---------------------------------------------------------------------------
// Segment starts via binary search on sorted batch
// ---------------------------------------------------------------------------
__global__ void segstart_kernel(const int* __restrict__ batch, int* __restrict__ seg, int n) {
    int s = blockIdx.x * blockDim.x + threadIdx.x;
    if (s <= S_SEG) {
        int lo = 0, hi = n;
        while (lo < hi) {
            int m = (lo + hi) >> 1;
            if (batch[m] < s) lo = m + 1; else hi = m;
        }
        seg[s] = lo;
    }
}

__global__ __launch_bounds__(128) void pool_kernel(const float* __restrict__ z,
                                                   const int* __restrict__ seg,
                                                   float* __restrict__ pooled) {
    int s = blockIdx.x;
    int fidx = threadIdx.x;
    int a = seg[s], b = seg[s + 1];
    float sum = 0.f;
    for (int r = a; r < b; r++) sum += z[(size_t)r * HID + fidx];
    float cnt = (float)(b - a);
    pooled[(size_t)s * EMB + fidx] = sum / fmaxf(cnt, 1.f);
}

// ---------------------------------------------------------------------------
// Precompute U[t][j] = pooled[t] . Wih[j] + bih[j] + bhh[j]
// ---------------------------------------------------------------------------
__global__ __launch_bounds__(256) void ucomp_kernel(const float* __restrict__ pooled,
                                                    const float* __restrict__ Wih,
                                                    const float* __restrict__ bih,
                                                    const float* __restrict__ bhh,
                                                    float* __restrict__ U) {
    __shared__ float xs[EMB];
    int t = blockIdx.x;
    int j = threadIdx.x;
    if (j < EMB) xs[j] = pooled[(size_t)t * EMB + j];
    __syncthreads();
    const float* wr = Wih + (size_t)j * EMB;
    float a0 = 0.f, a1 = 0.f, a2 = 0.f, a3 = 0.f;
#pragma unroll
    for (int k = 0; k < EMB; k += 16) {
        float4 w0 = *(const float4*)&wr[k];
        float4 w1 = *(const float4*)&wr[k + 4];
        float4 w2 = *(const float4*)&wr[k + 8];
        float4 w3 = *(const float4*)&wr[k + 12];
        a0 += w0.x * xs[k]      + w0.y * xs[k + 1]  + w0.z * xs[k + 2]  + w0.w * xs[k + 3];
        a1 += w1.x * xs[k + 4]  + w1.y * xs[k + 5]  + w1.z * xs[k + 6]  + w1.w * xs[k + 7];
        a2 += w2.x * xs[k + 8]  + w2.y * xs[k + 9]  + w2.z * xs[k + 10] + w2.w * xs[k + 11];
        a3 += w3.x * xs[k + 12] + w3.y * xs[k + 13] + w3.z * xs[k + 14] + w3.w * xs[k + 15];
    }
    U[(size_t)t * RNN_HID + j] = ((a0 + a1) + (a2 + a3)) + bih[j] + bhh[j];
}

// ---------------------------------------------------------------------------
// Serial tanh RNN: h_t = tanh(U[t] + Whh @ h_{t-1})
// 256 threads (4 waves). Thread (jb = tid>>3, q = tid&7) owns 8 outputs
// (j = 8jb..8jb+7) over k-slice [32q, 32q+32), with all 256 Whh weights
// register-resident (pre-rotated to match the read schedule).
//
// LDS traffic: 8 ds_read_b128 per thread per step = 32 wave-reads/step.
// Bank schedule: at unroll c, lane reads float4 f = q*8 + ((c+q)&7) ->
// bank-start ((c+q)&7)*4; the 8 distinct q-addresses partition all 32 banks
// (width 4, stride 4), same-q lanes broadcast => conflict-free.
// Reduce across the 8-lane k-group: 3 shfl_xor rounds; branch-free select.
// Double-buffered hb, one barrier/step, U[t+1] prefetched.
// ---------------------------------------------------------------------------
__global__ __launch_bounds__(256, 1) void rnn_kernel(const float* __restrict__ U,
                                                     const float* __restrict__ Whh,
                                                     float* __restrict__ hs) {
    __shared__ float hb[2][RNN_HID];
    int tid = threadIdx.x;
    int jb = tid >> 3;         // output-group 0..31 (outputs 8jb..8jb+7)
    int q  = tid & 7;          // k-slice 0..7 (k in [32q, 32q+32))
    int j  = tid;              // == 8*jb + q: the output this thread finalizes

    // Load weights pre-rotated: w[o][c] pairs with the float4 read at
    // f = q*8 + ((c+q)&7) in the main loop.
    float4 w[8][8];
#pragma unroll
    for (int o = 0; o < 8; o++) {
        const float* wrow = Whh + (size_t)(jb * 8 + o) * RNN_HID;
#pragma unroll
        for (int c = 0; c < 8; c++) {
            int f = q * 8 + ((c + q) & 7);
            w[o][c] = *(const float4*)&wrow[f * 4];
        }
    }

    hb[0][tid] = 0.f;          // 256 threads cover RNN_HID exactly
    __syncthreads();

    float u_next = U[j];       // t = 0
    int p = 0;
    for (int t = 0; t < S_SEG; t++) {
        float u = u_next;
        if (t + 1 < S_SEG) u_next = U[(size_t)(t + 1) * RNN_HID + j];

        float a0 = 0.f, a1 = 0.f, a2 = 0.f, a3 = 0.f;
        float a4 = 0.f, a5 = 0.f, a6 = 0.f, a7 = 0.f;
#pragma unroll
        for (int c = 0; c < 8; c++) {
            int f = q * 8 + ((c + q) & 7);
            float4 h4 = *(const float4*)&hb[p][f * 4];
            a0 += w[0][c].x * h4.x + w[0][c].y * h4.y + w[0][c].z * h4.z + w[0][c].w * h4.w;
            a1 += w[1][c].x * h4.x + w[1][c].y * h4.y + w[1][c].z * h4.z + w[1][c].w * h4.w;
            a2 += w[2][c].x * h4.x + w[2][c].y * h4.y + w[2][c].z * h4.z + w[2][c].w * h4.w;
            a3 += w[3][c].x * h4.x + w[3][c].y * h4.y + w[3][c].z * h4.z + w[3][c].w * h4.w;
            a4 += w[4][c].x * h4.x + w[4][c].y * h4.y + w[4][c].z * h4.z + w[4][c].w * h4.w;
            a5 += w[5][c].x * h4.x + w[5][c].y * h4.y + w[5][c].z * h4.z + w[5][c].w * h4.w;
            a6 += w[6][c].x * h4.x + w[6][c].y * h4.y + w[6][c].z * h4.z + w[6][c].w * h4.w;
            a7 += w[7][c].x * h4.x + w[7][c].y * h4.y + w[7][c].z * h4.z + w[7][c].w * h4.w;
        }
        // reduce each acc across the 8-lane k-group (lanes 8jb..8jb+7)
        a0 += __shfl_xor(a0, 1, 64); a0 += __shfl_xor(a0, 2, 64); a0 += __shfl_xor(a0, 4, 64);
        a1 += __shfl_xor(a1, 1, 64); a1 += __shfl_xor(a1, 2, 64); a1 += __shfl_xor(a1, 4, 64);
        a2 += __shfl_xor(a2, 1, 64); a2 += __shfl_xor(a2, 2, 64); a2 += __shfl_xor(a2, 4, 64);
        a3 += __shfl_xor(a3, 1, 64); a3 += __shfl_xor(a3, 2, 64); a3 += __shfl_xor(a3, 4, 64);
        a4 += __shfl_xor(a4, 1, 64); a4 += __shfl_xor(a4, 2, 64); a4 += __shfl_xor(a4, 4, 64);
        a5 += __shfl_xor(a5, 1, 64); a5 += __shfl_xor(a5, 2, 64); a5 += __shfl_xor(a5, 4, 64);
        a6 += __shfl_xor(a6, 1, 64); a6 += __shfl_xor(a6, 2, 64); a6 += __shfl_xor(a6, 4, 64);
        a7 += __shfl_xor(a7, 1, 64); a7 += __shfl_xor(a7, 2, 64); a7 += __shfl_xor(a7, 4, 64);
        // branch-free select: lane q takes acc[q]
        float s0 = (q & 1) ? a1 : a0;
        float s1 = (q & 1) ? a3 : a2;
        float s2 = (q & 1) ? a5 : a4;
        float s3 = (q & 1) ? a7 : a6;
        float t0 = (q & 2) ? s1 : s0;
        float t1 = (q & 2) ? s3 : s2;
        float acc = (q & 4) ? t1 : t0;

        float hn = tanhf(acc + u);
        hb[p ^ 1][j] = hn;
        hs[(size_t)t * RNN_HID + j] = hn;
        __syncthreads();
        p ^= 1;
    }
}

// ---------------------------------------------------------------------------
// Final linear + sigmoid: one wave per sequence position
// ---------------------------------------------------------------------------
__global__ __launch_bounds__(256) void logits_kernel(const float* __restrict__ hs,
                                                     const float* __restrict__ Wl,
                                                     const float* __restrict__ bl,
                                                     float* __restrict__ out) {
    int tid = threadIdx.x;
    int wave = tid >> 6, lane = tid & 63;
    int s = blockIdx.x * 4 + wave;
    float4 h = ((const float4*)&hs[(size_t)s * RNN_HID])[lane];
    float4 w0 = ((const float4*)Wl)[lane];
    float4 w1 = ((const float4*)(Wl + RNN_HID))[lane];
    float a0 = h.x * w0.x + h.y * w0.y + h.z * w0.z + h.w * w0.w;
    float a1 = h.x * w1.x + h.y * w1.y + h.z * w1.z + h.w * w1.w;
#pragma unroll
    for (int off = 32; off; off >>= 1) {
        a0 += __shfl_xor(a0, off, 64);
        a1 += __shfl_xor(a1, off, 64);
    }
    if (lane == 0) {
        out[s * 2 + 0] = 1.f / (1.f + expf(-(a0 + bl[0])));
        out[s * 2 + 1] = 1.f / (1.f + expf(-(a1 + bl[1])));
    }
}

// ---------------------------------------------------------------------------
extern "C" void kernel_launch(void* const* d_in, const int* in_sizes, int n_in,
                              void* d_out, int out_size, void* d_ws, size_t ws_size,
                              hipStream_t stream) {
    const float* x    = (const float*)d_in[0];
    const float* ew   = (const float*)d_in[1];
    const int*   src  = (const int*)d_in[2];
    const int*   dst  = (const int*)d_in[3];
    const int*   batch= (const int*)d_in[4];
    const float* W1   = (const float*)d_in[5];
    const float* b1   = (const float*)d_in[6];
    const float* W2   = (const float*)d_in[7];
    const float* b2   = (const float*)d_in[8];
    const float* W3   = (const float*)d_in[9];
    const float* b3   = (const float*)d_in[10];
    const float* Wih  = (const float*)d_in[11];
    const float* Whh  = (const float*)d_in[12];
    const float* bih  = (const float*)d_in[13];
    const float* bhh  = (const float*)d_in[14];
    const float* Wl   = (const float*)d_in[15];
    const float* bl   = (const float*)d_in[16];
    float* out = (float*)d_out;
    (void)in_sizes; (void)n_in; (void)out_size; (void)ws_size;

    char* ws = (char*)d_ws;
    size_t o = 0;
    auto alloc = [&](size_t bytes) -> char* {
        o = (o + 255) & ~(size_t)255;
        char* p = ws + o;
        o += bytes;
        return p;
    };
    float* bufA   = (float*)alloc((size_t)N_NODES * HID * 4);
    float* bufB   = (float*)alloc((size_t)N_NODES * HID * 4);
    int*   colA   = (int*)  alloc((size_t)N_EDGES * 4);
    float* wvA    = (float*)alloc((size_t)N_EDGES * 4);
    int*   rowp   = (int*)  alloc((size_t)(N_NODES + 1) * 4);
    int*   cursor = (int*)  alloc((size_t)N_NODES * 4);
    float* degw   = (float*)alloc((size_t)N_NODES * 4);
    float* dinv   = (float*)alloc((size_t)N_NODES * 4);
    int*   seg    = (int*)  alloc((size_t)(S_SEG + 1) * 4);
    float* pooled = (float*)alloc((size_t)S_SEG * EMB * 4);
    float* hs     = (float*)alloc((size_t)S_SEG * RNN_HID * 4);
    float* U      = (float*)alloc((size_t)S_SEG * RNN_HID * 4);

    // --- CSR build ---
    zero_kernel<<<(N_NODES + 255) / 256, 256, 0, stream>>>(cursor, degw, N_NODES);
    count_kernel<<<(N_EDGES + 255) / 256, 256, 0, stream>>>(dst, ew, cursor, degw, N_EDGES);
    scan_kernel<<<1, 1024, 0, stream>>>(cursor, rowp, N_NODES);
    dinv_kernel<<<(N_NODES + 255) / 256, 256, 0, stream>>>(degw, dinv, N_NODES);
    scatter_kernel<<<(N_EDGES + 255) / 256, 256, 0, stream>>>(src, dst, ew, cursor, colA, wvA, N_EDGES);

    // --- GCN layers ---
    gemm_kernel<<<N_NODES / 64, 256, 0, stream>>>(x, W1, bufA, F_INPUT);
    spmm_kernel<<<N_NODES / 4, 256, 0, stream>>>(bufA, rowp, colA, wvA, dinv, b1, bufB);
    gemm_kernel<<<N_NODES / 64, 256, 0, stream>>>(bufB, W2, bufA, HID);
    spmm_kernel<<<N_NODES / 4, 256, 0, stream>>>(bufA, rowp, colA, wvA, dinv, b2, bufB);
    gemm_kernel<<<N_NODES / 64, 256, 0, stream>>>(bufB, W3, bufA, HID);
    spmm_kernel<<<N_NODES / 4, 256, 0, stream>>>(bufA, rowp, colA, wvA, dinv, b3, bufB);

    // --- mean pool per subgraph ---
    segstart_kernel<<<(S_SEG + 1 + 255) / 256, 256, 0, stream>>>(batch, seg, N_NODES);
    pool_kernel<<<S_SEG, 128, 0, stream>>>(bufB, seg, pooled);

    // --- RNN: hoisted input projection, then serial loop ---
    ucomp_kernel<<<S_SEG, 256, 0, stream>>>(pooled, Wih, bih, bhh, U);
    rnn_kernel<<<1, 256, 0, stream>>>(U, Whh, hs);
    logits_kernel<<<S_SEG / 4, 256, 0, stream>>>(hs, Wl, bl, out);
}

// Round 10
// 1995.391 us; speedup vs baseline: 1.3467x; 1.2616x over previous
//
#include <hip/hip_runtime.h>
#include <math.h>

#define N_NODES 131072
#define N_EDGES 2097152
#define S_SEG   512
#define F_INPUT 64
#define HID     128
#define EMB     128
#define RNN_HID 256

// ---------------------------------------------------------------------------
// Graph preprocessing: counts + weighted degree
// ---------------------------------------------------------------------------
__global__ void zero_kernel(int* __restrict__ cnt, float* __restrict__ degw, int n) {
    int i = blockIdx.x * blockDim.x + threadIdx.x;
    if (i < n) { cnt[i] = 0; degw[i] = 0.f; }
}

__global__ void count_kernel(const int* __restrict__ dst, const float* __restrict__ ew,
                             int* __restrict__ cnt, float* __restrict__ degw, int e) {
    int i = blockIdx.x * blockDim.x + threadIdx.x;
    if (i < e) {
        int d = dst[i];
        atomicAdd(&cnt[d], 1);
        atomicAdd(&degw[d], ew[i]);
    }
}

// exclusive scan of cnt[n] -> row_ptr[n+1]; cnt becomes cursor (copy of row_ptr)
__global__ __launch_bounds__(1024) void scan_kernel(int* __restrict__ cnt,
                                                    int* __restrict__ row_ptr, int n) {
    __shared__ int sums[1024];
    int tid = threadIdx.x;
    int per = n / 1024;            // 128
    int base = tid * per;
    int s = 0;
    for (int k = 0; k < per; k++) s += cnt[base + k];
    sums[tid] = s;
    __syncthreads();
    for (int off = 1; off < 1024; off <<= 1) {
        int v = (tid >= off) ? sums[tid - off] : 0;
        __syncthreads();
        sums[tid] += v;
        __syncthreads();
    }
    int run = (tid > 0) ? sums[tid - 1] : 0;
    for (int k = 0; k < per; k++) {
        int v = cnt[base + k];
        row_ptr[base + k] = run;
        cnt[base + k] = run;       // cursor
        run += v;
    }
    if (tid == 1023) row_ptr[n] = run;
}

__global__ void dinv_kernel(const float* __restrict__ degw, float* __restrict__ dinv, int n) {
    int i = blockIdx.x * blockDim.x + threadIdx.x;
    if (i < n) dinv[i] = rsqrtf(degw[i] + 1.0f);   // +1 = self-loop weight
}

// scatter edges into CSR; fold the FULL symmetric norm into the stored value:
// wv[p] = dinv[dst] * ew * dinv[src]  (graph-only -> computed once, reused 3x)
__global__ void scatter_kernel(const int* __restrict__ src, const int* __restrict__ dst,
                               const float* __restrict__ ew, int* __restrict__ cursor,
                               const float* __restrict__ dinv,
                               int* __restrict__ col, float* __restrict__ wv, int e) {
    int i = blockIdx.x * blockDim.x + threadIdx.x;
    if (i < e) {
        int d = dst[i];
        int s = src[i];
        int p = atomicAdd(&cursor[d], 1);
        col[p] = s;
        wv[p]  = dinv[d] * ew[i] * dinv[s];
    }
}

// ---------------------------------------------------------------------------
// Dense GEMM: Y[M x 128] = X[M x K] @ W[K x 128], K in {64,128}, M % 64 == 0
// ---------------------------------------------------------------------------
__global__ __launch_bounds__(256) void gemm_kernel(const float* __restrict__ X,
                                                   const float* __restrict__ W,
                                                   float* __restrict__ Y, int K) {
    __shared__ float Xs[64][68];   // [k][m], padded
    __shared__ float Ws[64][128];  // [k][n]
    int tid = threadIdx.x;
    int m0 = blockIdx.x * 64;
    int tr = tid >> 5;             // 0..7
    int tc = tid & 31;             // 0..31
    int r0 = tr * 8;
    int c0 = tc * 4;
    float acc[8][4];
#pragma unroll
    for (int i = 0; i < 8; i++)
#pragma unroll
        for (int j = 0; j < 4; j++) acc[i][j] = 0.f;

    for (int kt = 0; kt < K; kt += 64) {
#pragma unroll
        for (int i = 0; i < 4; i++) {
            int lin = i * 256 + tid;
            int row = lin >> 4;
            int kq  = lin & 15;
            float4 v = *(const float4*)&X[(size_t)(m0 + row) * K + kt + kq * 4];
            Xs[kq * 4 + 0][row] = v.x;
            Xs[kq * 4 + 1][row] = v.y;
            Xs[kq * 4 + 2][row] = v.z;
            Xs[kq * 4 + 3][row] = v.w;
        }
#pragma unroll
        for (int i = 0; i < 8; i++) {
            int lin = i * 256 + tid;
            int kk = lin >> 5;
            int cq = lin & 31;
            *(float4*)&Ws[kk][cq * 4] = *(const float4*)&W[(size_t)(kt + kk) * 128 + cq * 4];
        }
        __syncthreads();
#pragma unroll
        for (int k = 0; k < 64; k++) {
            float4 b  = *(const float4*)&Ws[k][c0];
            float4 a0 = *(const float4*)&Xs[k][r0];
            float4 a1 = *(const float4*)&Xs[k][r0 + 4];
            float a[8] = {a0.x, a0.y, a0.z, a0.w, a1.x, a1.y, a1.z, a1.w};
            float bb[4] = {b.x, b.y, b.z, b.w};
#pragma unroll
            for (int i = 0; i < 8; i++)
#pragma unroll
                for (int j = 0; j < 4; j++) acc[i][j] += a[i] * bb[j];
        }
        __syncthreads();
    }
#pragma unroll
    for (int i = 0; i < 8; i++) {
        float4 v = make_float4(acc[i][0], acc[i][1], acc[i][2], acc[i][3]);
        *(float4*)&Y[(size_t)(m0 + r0 + i) * 128 + c0] = v;
    }
}

// ---------------------------------------------------------------------------
// SpMM: out[i][:] = relu( dinv[i]^2*t[i][:] + sum_p wv[p]*t[col[p]][:] + b )
// wv already carries the full symmetric norm. Edge loop unrolled x4 so four
// independent 512B row-gathers are in flight per wave (latency-bound fix).
// ---------------------------------------------------------------------------
__global__ __launch_bounds__(256) void spmm_kernel(const float* __restrict__ t,
                                                   const int* __restrict__ row_ptr,
                                                   const int* __restrict__ col,
                                                   const float* __restrict__ wv,
                                                   const float* __restrict__ dinv,
                                                   const float* __restrict__ bias,
                                                   float* __restrict__ out) {
    int wave = threadIdx.x >> 6;
    int lane = threadIdx.x & 63;
    int i = blockIdx.x * 4 + wave;
    int f = lane * 2;
    float di = dinv[i];
    float2 self = *(const float2*)&t[(size_t)i * HID + f];
    float sc = di * di;
    float ax = sc * self.x, ay = sc * self.y;
    int p0 = row_ptr[i], p1 = row_ptr[i + 1];
    int p = p0;
    for (; p + 4 <= p1; p += 4) {
        int c0 = col[p];
        int c1 = col[p + 1];
        int c2 = col[p + 2];
        int c3 = col[p + 3];
        float w0 = wv[p];
        float w1 = wv[p + 1];
        float w2 = wv[p + 2];
        float w3 = wv[p + 3];
        float2 v0 = *(const float2*)&t[(size_t)c0 * HID + f];
        float2 v1 = *(const float2*)&t[(size_t)c1 * HID + f];
        float2 v2 = *(const float2*)&t[(size_t)c2 * HID + f];
        float2 v3 = *(const float2*)&t[(size_t)c3 * HID + f];
        ax += w0 * v0.x + w1 * v1.x + w2 * v2.x + w3 * v3.x;
        ay += w0 * v0.y + w1 * v1.y + w2 * v2.y + w3 * v3.y;
    }
    for (; p < p1; p++) {
        int c = col[p];
        float coef = wv[p];
        float2 v = *(const float2*)&t[(size_t)c * HID + f];
        ax += coef * v.x;
        ay += coef * v.y;
    }
    float2 b = *(const float2*)&bias[f];
    ax = fmaxf(ax + b.x, 0.f);
    ay = fmaxf(ay + b.y, 0.f);
    float2 r; r.x = ax; r.y = ay;
    *(float2*)&out[(size_t)i * HID + f] = r;
}

// ---------------------------------------------------------------------------
// Segment starts via binary search on sorted batch
// ---------------------------------------------------------------------------
__global__ void segstart_kernel(const int* __restrict__ batch, int* __restrict__ seg, int n) {
    int s = blockIdx.x * blockDim.x + threadIdx.x;
    if (s <= S_SEG) {
        int lo = 0, hi = n;
        while (lo < hi) {
            int m = (lo + hi) >> 1;
            if (batch[m] < s) lo = m + 1; else hi = m;
        }
        seg[s] = lo;
    }
}

__global__ __launch_bounds__(128) void pool_kernel(const float* __restrict__ z,
                                                   const int* __restrict__ seg,
                                                   float* __restrict__ pooled) {
    int s = blockIdx.x;
    int fidx = threadIdx.x;
    int a = seg[s], b = seg[s + 1];
    float sum = 0.f;
    for (int r = a; r < b; r++) sum += z[(size_t)r * HID + fidx];
    float cnt = (float)(b - a);
    pooled[(size_t)s * EMB + fidx] = sum / fmaxf(cnt, 1.f);
}

// ---------------------------------------------------------------------------
// Precompute U[t][j] = pooled[t] . Wih[j] + bih[j] + bhh[j]
// ---------------------------------------------------------------------------
__global__ __launch_bounds__(256) void ucomp_kernel(const float* __restrict__ pooled,
                                                    const float* __restrict__ Wih,
                                                    const float* __restrict__ bih,
                                                    const float* __restrict__ bhh,
                                                    float* __restrict__ U) {
    __shared__ float xs[EMB];
    int t = blockIdx.x;
    int j = threadIdx.x;
    if (j < EMB) xs[j] = pooled[(size_t)t * EMB + j];
    __syncthreads();
    const float* wr = Wih + (size_t)j * EMB;
    float a0 = 0.f, a1 = 0.f, a2 = 0.f, a3 = 0.f;
#pragma unroll
    for (int k = 0; k < EMB; k += 16) {
        float4 w0 = *(const float4*)&wr[k];
        float4 w1 = *(const float4*)&wr[k + 4];
        float4 w2 = *(const float4*)&wr[k + 8];
        float4 w3 = *(const float4*)&wr[k + 12];
        a0 += w0.x * xs[k]      + w0.y * xs[k + 1]  + w0.z * xs[k + 2]  + w0.w * xs[k + 3];
        a1 += w1.x * xs[k + 4]  + w1.y * xs[k + 5]  + w1.z * xs[k + 6]  + w1.w * xs[k + 7];
        a2 += w2.x * xs[k + 8]  + w2.y * xs[k + 9]  + w2.z * xs[k + 10] + w2.w * xs[k + 11];
        a3 += w3.x * xs[k + 12] + w3.y * xs[k + 13] + w3.z * xs[k + 14] + w3.w * xs[k + 15];
    }
    U[(size_t)t * RNN_HID + j] = ((a0 + a1) + (a2 + a3)) + bih[j] + bhh[j];
}

// ---------------------------------------------------------------------------
// Serial tanh RNN: h_t = tanh(U[t] + Whh @ h_{t-1})
// 512 threads (8 waves, 2/SIMD). Thread (jg = tid>>3, q = tid&7) owns
// 4 outputs (j = 4jg..4jg+3) over k-slice [32q, 32q+32): 128 weights =
// 32 float4 VGPRs + ~45 working ~= 175 regs -> FITS (round-9 lesson:
// o=8 needed 256 weight regs -> compiler demoted to L2 streaming, 1.65us/step).
// LDS: 8 ds_read_b128/thread/step, rotation f = q*8+((c+q)&7): the 8 distinct
// q-addresses hit bank-starts {0,4,..,28} (full partition, broadcast within q)
// -> 0 conflicts (verified by round-9 counters).
// Reduce over the 8-lane k-group: 3 shfl_xor rounds x 4 accs; lane q<4 writes
// output 4jg+q. Double-buffered hb, one barrier/step, U[t+1] prefetched.
// ---------------------------------------------------------------------------
__global__ __launch_bounds__(512, 2) void rnn_kernel(const float* __restrict__ U,
                                                     const float* __restrict__ Whh,
                                                     float* __restrict__ hs) {
    __shared__ float hb[2][RNN_HID];
    int tid = threadIdx.x;
    int jg = tid >> 3;         // output-group 0..63 (outputs 4jg..4jg+3)
    int q  = tid & 7;          // k-slice 0..7 (k in [32q, 32q+32))

    // weights pre-rotated to match the read schedule f = q*8 + ((c+q)&7)
    float4 w[4][8];
#pragma unroll
    for (int o = 0; o < 4; o++) {
        const float* wrow = Whh + (size_t)(jg * 4 + o) * RNN_HID;
#pragma unroll
        for (int c = 0; c < 8; c++) {
            int f = q * 8 + ((c + q) & 7);
            w[o][c] = *(const float4*)&wrow[f * 4];
        }
    }

    if (tid < RNN_HID) hb[0][tid] = 0.f;
    __syncthreads();

    int j_out = jg * 4 + (q & 3);      // output this thread finalizes (q<4 writes)
    float u_next = U[j_out];           // t = 0
    int p = 0;
    for (int t = 0; t < S_SEG; t++) {
        float u = u_next;
        if (t + 1 < S_SEG) u_next = U[(size_t)(t + 1) * RNN_HID + j_out];

        float a0 = 0.f, a1 = 0.f, a2 = 0.f, a3 = 0.f;
#pragma unroll
        for (int c = 0; c < 8; c++) {
            int f = q * 8 + ((c + q) & 7);
            float4 h4 = *(const float4*)&hb[p][f * 4];
            a0 += w[0][c].x * h4.x + w[0][c].y * h4.y + w[0][c].z * h4.z + w[0][c].w * h4.w;
            a1 += w[1][c].x * h4.x + w[1][c].y * h4.y + w[1][c].z * h4.z + w[1][c].w * h4.w;
            a2 += w[2][c].x * h4.x + w[2][c].y * h4.y + w[2][c].z * h4.z + w[2][c].w * h4.w;
            a3 += w[3][c].x * h4.x + w[3][c].y * h4.y + w[3][c].z * h4.z + w[3][c].w * h4.w;
        }
        // reduce each acc across the 8-lane k-group (lanes 8jg..8jg+7)
        a0 += __shfl_xor(a0, 1, 64); a0 += __shfl_xor(a0, 2, 64); a0 += __shfl_xor(a0, 4, 64);
        a1 += __shfl_xor(a1, 1, 64); a1 += __shfl_xor(a1, 2, 64); a1 += __shfl_xor(a1, 4, 64);
        a2 += __shfl_xor(a2, 1, 64); a2 += __shfl_xor(a2, 2, 64); a2 += __shfl_xor(a2, 4, 64);
        a3 += __shfl_xor(a3, 1, 64); a3 += __shfl_xor(a3, 2, 64); a3 += __shfl_xor(a3, 4, 64);
        // branch-free select: lane q takes acc[q&3]
        float s0 = (q & 1) ? a1 : a0;
        float s1 = (q & 1) ? a3 : a2;
        float acc = (q & 2) ? s1 : s0;

        float hn = tanhf(acc + u);
        if (q < 4) {
            hb[p ^ 1][j_out] = hn;
            hs[(size_t)t * RNN_HID + j_out] = hn;
        }
        __syncthreads();
        p ^= 1;
    }
}

// ---------------------------------------------------------------------------
// Final linear + sigmoid: one wave per sequence position
// ---------------------------------------------------------------------------
__global__ __launch_bounds__(256) void logits_kernel(const float* __restrict__ hs,
                                                     const float* __restrict__ Wl,
                                                     const float* __restrict__ bl,
                                                     float* __restrict__ out) {
    int tid = threadIdx.x;
    int wave = tid >> 6, lane = tid & 63;
    int s = blockIdx.x * 4 + wave;
    float4 h = ((const float4*)&hs[(size_t)s * RNN_HID])[lane];
    float4 w0 = ((const float4*)Wl)[lane];
    float4 w1 = ((const float4*)(Wl + RNN_HID))[lane];
    float a0 = h.x * w0.x + h.y * w0.y + h.z * w0.z + h.w * w0.w;
    float a1 = h.x * w1.x + h.y * w1.y + h.z * w1.z + h.w * w1.w;
#pragma unroll
    for (int off = 32; off; off >>= 1) {
        a0 += __shfl_xor(a0, off, 64);
        a1 += __shfl_xor(a1, off, 64);
    }
    if (lane == 0) {
        out[s * 2 + 0] = 1.f / (1.f + expf(-(a0 + bl[0])));
        out[s * 2 + 1] = 1.f / (1.f + expf(-(a1 + bl[1])));
    }
}

// ---------------------------------------------------------------------------
extern "C" void kernel_launch(void* const* d_in, const int* in_sizes, int n_in,
                              void* d_out, int out_size, void* d_ws, size_t ws_size,
                              hipStream_t stream) {
    const float* x    = (const float*)d_in[0];
    const float* ew   = (const float*)d_in[1];
    const int*   src  = (const int*)d_in[2];
    const int*   dst  = (const int*)d_in[3];
    const int*   batch= (const int*)d_in[4];
    const float* W1   = (const float*)d_in[5];
    const float* b1   = (const float*)d_in[6];
    const float* W2   = (const float*)d_in[7];
    const float* b2   = (const float*)d_in[8];
    const float* W3   = (const float*)d_in[9];
    const float* b3   = (const float*)d_in[10];
    const float* Wih  = (const float*)d_in[11];
    const float* Whh  = (const float*)d_in[12];
    const float* bih  = (const float*)d_in[13];
    const float* bhh  = (const float*)d_in[14];
    const float* Wl   = (const float*)d_in[15];
    const float* bl   = (const float*)d_in[16];
    float* out = (float*)d_out;
    (void)in_sizes; (void)n_in; (void)out_size; (void)ws_size;

    char* ws = (char*)d_ws;
    size_t o = 0;
    auto alloc = [&](size_t bytes) -> char* {
        o = (o + 255) & ~(size_t)255;
        char* p = ws + o;
        o += bytes;
        return p;
    };
    float* bufA   = (float*)alloc((size_t)N_NODES * HID * 4);
    float* bufB   = (float*)alloc((size_t)N_NODES * HID * 4);
    int*   colA   = (int*)  alloc((size_t)N_EDGES * 4);
    float* wvA    = (float*)alloc((size_t)N_EDGES * 4);
    int*   rowp   = (int*)  alloc((size_t)(N_NODES + 1) * 4);
    int*   cursor = (int*)  alloc((size_t)N_NODES * 4);
    float* degw   = (float*)alloc((size_t)N_NODES * 4);
    float* dinv   = (float*)alloc((size_t)N_NODES * 4);
    int*   seg    = (int*)  alloc((size_t)(S_SEG + 1) * 4);
    float* pooled = (float*)alloc((size_t)S_SEG * EMB * 4);
    float* hs     = (float*)alloc((size_t)S_SEG * RNN_HID * 4);
    float* U      = (float*)alloc((size_t)S_SEG * RNN_HID * 4);

    // --- CSR build (edge norms folded in once, reused by all 3 layers) ---
    zero_kernel<<<(N_NODES + 255) / 256, 256, 0, stream>>>(cursor, degw, N_NODES);
    count_kernel<<<(N_EDGES + 255) / 256, 256, 0, stream>>>(dst, ew, cursor, degw, N_EDGES);
    scan_kernel<<<1, 1024, 0, stream>>>(cursor, rowp, N_NODES);
    dinv_kernel<<<(N_NODES + 255) / 256, 256, 0, stream>>>(degw, dinv, N_NODES);
    scatter_kernel<<<(N_EDGES + 255) / 256, 256, 0, stream>>>(src, dst, ew, cursor, dinv, colA, wvA, N_EDGES);

    // --- GCN layers ---
    gemm_kernel<<<N_NODES / 64, 256, 0, stream>>>(x, W1, bufA, F_INPUT);
    spmm_kernel<<<N_NODES / 4, 256, 0, stream>>>(bufA, rowp, colA, wvA, dinv, b1, bufB);
    gemm_kernel<<<N_NODES / 64, 256, 0, stream>>>(bufB, W2, bufA, HID);
    spmm_kernel<<<N_NODES / 4, 256, 0, stream>>>(bufA, rowp, colA, wvA, dinv, b2, bufB);
    gemm_kernel<<<N_NODES / 64, 256, 0, stream>>>(bufB, W3, bufA, HID);
    spmm_kernel<<<N_NODES / 4, 256, 0, stream>>>(bufA, rowp, colA, wvA, dinv, b3, bufB);

    // --- mean pool per subgraph ---
    segstart_kernel<<<(S_SEG + 1 + 255) / 256, 256, 0, stream>>>(batch, seg, N_NODES);
    pool_kernel<<<S_SEG, 128, 0, stream>>>(bufB, seg, pooled);

    // --- RNN: hoisted input projection, then serial loop ---
    ucomp_kernel<<<S_SEG, 256, 0, stream>>>(pooled, Wih, bih, bhh, U);
    rnn_kernel<<<1, 512, 0, stream>>>(U, Whh, hs);
    logits_kernel<<<S_SEG / 4, 256, 0, stream>>>(hs, Wl, bl, out);
}